// Round 6
// baseline (425.040 us; speedup 1.0000x reference)
//
#include <hip/hip_runtime.h>
#include <hip/hip_bf16.h>

typedef __attribute__((ext_vector_type(8))) short bf16x8;
typedef __attribute__((ext_vector_type(4))) float f32x4;
typedef unsigned short u16;
typedef unsigned int u32;

__device__ __forceinline__ u32 bf16_rne(float f) {
  u32 u = __float_as_uint(f);
  return (u + 0x7FFFu + ((u >> 16) & 1u)) >> 16;
}
__device__ __forceinline__ float bf16_val(u32 b) { return __uint_as_float(b << 16); }

__device__ __forceinline__ void g2l16(const u16* g, u16* l) {
  __builtin_amdgcn_global_load_lds(
      (const __attribute__((address_space(1))) u32*)g,
      (__attribute__((address_space(3))) u32*)l, 16, 0, 0);
}

// ---- split fp32 -> interleaved [blk][2][chunkElems] bf16 hi/lo ----
// chunk4 = chunkElems/4 (float4 granularity)
__global__ void split_pairs(const float* __restrict__ in, u16* __restrict__ out,
                            int n4, int chunk4) {
  int i = blockIdx.x * 256 + threadIdx.x;
  if (i >= n4) return;
  float4 v = ((const float4*)in)[i];
  u32 h0 = bf16_rne(v.x), h1 = bf16_rne(v.y), h2 = bf16_rne(v.z), h3 = bf16_rne(v.w);
  u32 l0 = bf16_rne(v.x - bf16_val(h0));
  u32 l1 = bf16_rne(v.y - bf16_val(h1));
  u32 l2 = bf16_rne(v.z - bf16_val(h2));
  u32 l3 = bf16_rne(v.w - bf16_val(h3));
  ushort4 hv; hv.x = (u16)h0; hv.y = (u16)h1; hv.z = (u16)h2; hv.w = (u16)h3;
  ushort4 lv; lv.x = (u16)l0; lv.y = (u16)l1; lv.z = (u16)l2; lv.w = (u16)l3;
  int blk = i / chunk4, off = i % chunk4;
  ((ushort4*)out)[(size_t)blk * 2 * chunk4 + off] = hv;
  ((ushort4*)out)[(size_t)blk * 2 * chunk4 + chunk4 + off] = lv;
}

// ---- transpose each 256x256 fp32 slice, split into interleaved hi/lo ----
// out layout: [z][2][256][256]
__global__ void split_transpose256(const float* __restrict__ in, u16* __restrict__ out) {
  __shared__ float tile[32][33];
  const size_t zin = (size_t)blockIdx.z * 65536;
  const size_t zout = (size_t)blockIdx.z * 131072;
  const int tx = threadIdx.x, ty = threadIdx.y;
#pragma unroll
  for (int i = 0; i < 4; ++i) {
    int y = blockIdx.y * 32 + ty + i * 8;
    int x = blockIdx.x * 32 + tx;
    tile[ty + i * 8][tx] = in[zin + (size_t)y * 256 + x];
  }
  __syncthreads();
#pragma unroll
  for (int i = 0; i < 4; ++i) {
    float v = tile[tx][ty + i * 8];
    u32 hb = bf16_rne(v);
    u32 lb = bf16_rne(v - bf16_val(hb));
    size_t idx = (size_t)(blockIdx.x * 32 + ty + i * 8) * 256 + blockIdx.y * 32 + tx;
    out[zout + idx] = (u16)hb;
    out[zout + 65536 + idx] = (u16)lb;
  }
}

// ---------------- fused priors-GEMM (split-bf16) + dynamic routing ----------------
// 512 threads = 8 waves, wave grid mg(2) x eg(4).
// Wave (mg,eg) owns P rows [mg*R/2 .. +R/2) x cols [eg*64 .. +64).
// P[b,e]: b = mg*(R/2) + mt*16 + q*4 + r, e = eg*64 + ct*16 + li.
// LDS chunk c: 1024 B; lane i of the DMA holds (row = i&15, qslab = i>>4),
// so MFMA fragment reads are chunkbase + lane*16 (stride-1, conflict-free).
template <int R>
__global__ __launch_bounds__(512, 4) void caps_route(
    const u16* __restrict__ Ain,     // [64][2][R][256] interleaved hi/lo
    const u16* __restrict__ Win,     // [KN][2][256][256] interleaved hi/lo (transposed [e][d])
    u16* __restrict__ o1,            // stage1 out: [64][2][KN][256]
    float* __restrict__ outp,        // stage2 out
    int KN, int stage) {
  constexpr int MTW = R / 32;        // m-tiles per wave
  constexpr int NA = R / 16;         // A-hi chunks
  constexpr int NTOT = 2 * NA + 32;  // + B hi/lo chunks
  constexpr int CPW = NTOT / 8;      // chunks per wave
  __shared__ __align__(16) u16 BUF[NTOT * 512];   // [Ahi | Alo | Bhi | Blo]
  __shared__ __align__(16) float smat[2][256];
  __shared__ __align__(16) float wlog[4][R];
  __shared__ float logits[R];
  __shared__ __align__(16) float probs[R];
  __shared__ float sqpart[4];

  const int tid = threadIdx.x;
  const int w = tid >> 6, lane = tid & 63, q = lane >> 4, li = lane & 15;
  const int mg = w >> 2, eg = w & 3;
  const int kk = blockIdx.x >> 6;   // weight slice (h or c)
  const int a  = blockIdx.x & 63;

  const u16* Aab = Ain + (size_t)a * 2 * R * 256;
  const u16* Wkk = Win + (size_t)kk * 131072;

  f32x4 acc[MTW][4] = {};

  const int laneoff = (lane & 15) * 256 + (lane >> 4) * 8;  // src elem offset in chunk
  const int fo = (q * 16 + li) * 8;                          // frag offset (u16) in chunk

  // ---- GEMM: P = A (R x 256) @ W[kk] (256 x 256), split-bf16 3-MFMA ----
  for (int ks = 0; ks < 8; ++ks) {
    const int k0 = ks * 32;
#pragma unroll
    for (int j = 0; j < CPW; ++j) {
      int c = w * CPW + j;
      const u16* g = (c < 2 * NA) ? (Aab + c * 4096) : (Wkk + (c - 2 * NA) * 4096);
      g2l16(g + laneoff + k0, BUF + c * 512);
    }
    __syncthreads();   // drains DMA (vmcnt) before reads
    bf16x8 bh[4], bl[4];
#pragma unroll
    for (int ct = 0; ct < 4; ++ct) {
      bh[ct] = *(const bf16x8*)(BUF + (2 * NA + eg * 4 + ct) * 512 + fo);
      bl[ct] = *(const bf16x8*)(BUF + (2 * NA + 16 + eg * 4 + ct) * 512 + fo);
    }
#pragma unroll
    for (int mt = 0; mt < MTW; ++mt) {
      bf16x8 ah = *(const bf16x8*)(BUF + (mg * MTW + mt) * 512 + fo);
      bf16x8 al = *(const bf16x8*)(BUF + (NA + mg * MTW + mt) * 512 + fo);
#pragma unroll
      for (int ct = 0; ct < 4; ++ct) {
        acc[mt][ct] = __builtin_amdgcn_mfma_f32_16x16x32_bf16(al, bh[ct], acc[mt][ct], 0, 0, 0);
        acc[mt][ct] = __builtin_amdgcn_mfma_f32_16x16x32_bf16(ah, bl[ct], acc[mt][ct], 0, 0, 0);
        acc[mt][ct] = __builtin_amdgcn_mfma_f32_16x16x32_bf16(ah, bh[ct], acc[mt][ct], 0, 0, 0);
      }
    }
    __syncthreads();
  }

  // ---- dynamic routing (3 iterations) on register-resident P ----
  const float invR = 1.0f / R;
  float v[4];

  for (int iter = 0; iter < 3; ++iter) {
    // s[e] = sum_b probs[b] * P[b,e] : in-lane over (mt,r), shfl over q, LDS over mg
    float sp[4];
#pragma unroll
    for (int ct = 0; ct < 4; ++ct) {
      float t = 0.f;
#pragma unroll
      for (int mt = 0; mt < MTW; ++mt) {
        float4 p4;
        if (iter == 0) { p4.x = invR; p4.y = invR; p4.z = invR; p4.w = invR; }
        else           { p4 = *(const float4*)&probs[mg * (R / 2) + mt * 16 + q * 4]; }
        t += p4.x * acc[mt][ct][0];
        t += p4.y * acc[mt][ct][1];
        t += p4.z * acc[mt][ct][2];
        t += p4.w * acc[mt][ct][3];
      }
      t += __shfl_xor(t, 16);
      t += __shfl_xor(t, 32);
      sp[ct] = t;
    }
    if (q == 0) {
#pragma unroll
      for (int ct = 0; ct < 4; ++ct) smat[mg][eg * 64 + ct * 16 + li] = sp[ct];
    }
    __syncthreads();
    float s[4];
#pragma unroll
    for (int ct = 0; ct < 4; ++ct) {
      int e = eg * 64 + ct * 16 + li;
      s[ct] = smat[0][e] + smat[1][e];
    }
    // squash
    float ss = s[0] * s[0] + s[1] * s[1] + s[2] * s[2] + s[3] * s[3];
    ss += __shfl_xor(ss, 1);
    ss += __shfl_xor(ss, 2);
    ss += __shfl_xor(ss, 4);
    ss += __shfl_xor(ss, 8);
    if (mg == 0 && lane == 0) sqpart[eg] = ss;
    __syncthreads();
    float sq = sqpart[0] + sqpart[1] + sqpart[2] + sqpart[3];
    float scale = (sq > 0.f) ? sq / ((1.0f + sq) * sqrtf(sq)) : 0.f;
#pragma unroll
    for (int ct = 0; ct < 4; ++ct) v[ct] = s[ct] * scale;

    if (iter < 2) {
      // logits[b] += sum_e P[b,e] * v[e] : in-lane over ct, shfl over li, LDS over eg
#pragma unroll
      for (int mt = 0; mt < MTW; ++mt) {
        float t0, t1, t2, t3;
        {
          float t = acc[mt][0][0] * v[0] + acc[mt][1][0] * v[1] +
                    acc[mt][2][0] * v[2] + acc[mt][3][0] * v[3];
          t += __shfl_xor(t, 1); t += __shfl_xor(t, 2);
          t += __shfl_xor(t, 4); t += __shfl_xor(t, 8);
          t0 = t;
        }
        {
          float t = acc[mt][0][1] * v[0] + acc[mt][1][1] * v[1] +
                    acc[mt][2][1] * v[2] + acc[mt][3][1] * v[3];
          t += __shfl_xor(t, 1); t += __shfl_xor(t, 2);
          t += __shfl_xor(t, 4); t += __shfl_xor(t, 8);
          t1 = t;
        }
        {
          float t = acc[mt][0][2] * v[0] + acc[mt][1][2] * v[1] +
                    acc[mt][2][2] * v[2] + acc[mt][3][2] * v[3];
          t += __shfl_xor(t, 1); t += __shfl_xor(t, 2);
          t += __shfl_xor(t, 4); t += __shfl_xor(t, 8);
          t2 = t;
        }
        {
          float t = acc[mt][0][3] * v[0] + acc[mt][1][3] * v[1] +
                    acc[mt][2][3] * v[2] + acc[mt][3][3] * v[3];
          t += __shfl_xor(t, 1); t += __shfl_xor(t, 2);
          t += __shfl_xor(t, 4); t += __shfl_xor(t, 8);
          t3 = t;
        }
        if (li == 0)
          *(float4*)&wlog[eg][mg * (R / 2) + mt * 16 + q * 4] = make_float4(t0, t1, t2, t3);
      }
      __syncthreads();
      if (tid < R) {
        float l = (iter == 0 ? 0.f : logits[tid]);
        l += wlog[0][tid] + wlog[1][tid] + wlog[2][tid] + wlog[3][tid];
        logits[tid] = l;
      }
      __syncthreads();
      if (w == 0) {  // softmax over R logits, wave 0
        float l0 = logits[lane];
        float l1 = (R == 128) ? logits[lane + 64] : -3.0e38f;
        float m = fmaxf(l0, l1);
#pragma unroll
        for (int d2 = 1; d2 < 64; d2 <<= 1) m = fmaxf(m, __shfl_xor(m, d2));
        float e0 = expf(l0 - m);
        float e1 = (R == 128) ? expf(l1 - m) : 0.f;
        float zz = e0 + e1;
#pragma unroll
        for (int d2 = 1; d2 < 64; d2 <<= 1) zz += __shfl_xor(zz, d2);
        float inv = 1.0f / zz;
        probs[lane] = e0 * inv;
        if (R == 128) probs[lane + 64] = e1 * inv;
      }
      __syncthreads();
    }
  }

  // ---- epilogue. stage1 -> o1[a][2][KN][256] split; stage2 -> fp32 out[kk][a][e] ----
  if (mg == 0 && q == 0) {
    if (stage == 1) {
      size_t ob = (size_t)a * 2 * KN * 256 + (size_t)kk * 256;
#pragma unroll
      for (int ct = 0; ct < 4; ++ct) {
        int e = eg * 64 + ct * 16 + li;
        u32 hb = bf16_rne(v[ct]);
        u32 lb = bf16_rne(v[ct] - bf16_val(hb));
        o1[ob + e] = (u16)hb;
        o1[ob + (size_t)KN * 256 + e] = (u16)lb;
      }
    } else {
      size_t ob = ((size_t)kk * 64 + a) * 256;
#pragma unroll
      for (int ct = 0; ct < 4; ++ct) {
        int e = eg * 64 + ct * 16 + li;
        outp[ob + e] = v[ct];
      }
    }
  }
}

extern "C" void kernel_launch(void* const* d_in, const int* in_sizes, int n_in,
                              void* d_out, int out_size, void* d_ws, size_t ws_size,
                              hipStream_t stream) {
  const float* x  = (const float*)d_in[0];   // [64][128][256]
  const float* w1 = (const float*)d_in[1];   // [64][256][256]
  const float* wc = (const float*)d_in[2];   // [32][256][256]
  float* out = (float*)d_out;                // [32][64][256]

  char* ws = (char*)d_ws;
  u16* x2  = (u16*)(ws);                     // [64][2][128][256]  16 MB
  u16* w12 = (u16*)(ws + (16u << 20));       // [64][2][256][256]  16 MB
  u16* wc2 = (u16*)(ws + (32u << 20));       // [32][2][256][256]   8 MB
  u16* o1  = (u16*)(ws + (40u << 20));       // [64][2][64][256]    4 MB

  // x: 64*128*256 = 2,097,152 elems = 524,288 float4s; per-a chunk = 32768 elems (8192 f4)
  split_pairs<<<2048, 256, 0, stream>>>(x, x2, 524288, 8192);
  split_transpose256<<<dim3(8, 8, 64), dim3(32, 8), 0, stream>>>(w1, w12);
  split_transpose256<<<dim3(8, 8, 32), dim3(32, 8), 0, stream>>>(wc, wc2);
  caps_route<128><<<64 * 64, 512, 0, stream>>>(x2, w12, o1, nullptr, 64, 1);
  caps_route<64><<<32 * 64, 512, 0, stream>>>(o1, wc2, nullptr, out, 32, 2);
}